// Round 10
// baseline (122.878 us; speedup 1.0000x reference)
//
#include <hip/hip_runtime.h>
#include <hip/hip_fp16.h>
#include <math.h>

// Folded_Encoder fused, round 5 (MI355X / gfx950).
// B=8192, S=50, D=64.
// prep_kernel: (a) uv2e fp32 -> fp16 ktab in ws (streams table, re-warms L3
//              after the harness's L3-flushing poison fill), (b) pre-gathers
//              q=uv2e[nodes] and feat[nodes] rows into a compact qf buffer.
// main kernel: 512 blocks x 512 thr, 2 row-batches/block (W1 staged once),
//              wave = 1 row = 4 S-quarter groups x 16 d-lanes, direct global
//              idx loads (no seqbuf), 13 gathers in flight, exp2 softmax,
//              DPP group reduce, swizzled-LDS W1 linear + readlane broadcast.

#define DD      64
#define SS      50
#define WPB     8               // waves (= rows per batch) per 512-thread block
#define BATCHES 2
#define SCALE_L2E 0.180336880f  // 0.125 * log2(e)

__device__ __forceinline__ float rdlane_f(float v, int l) {
    return __int_as_float(__builtin_amdgcn_readlane(__float_as_int(v), l));
}

template <int CTRL>
__device__ __forceinline__ float dpp_add(float x) {
    int r = __builtin_amdgcn_update_dpp(0, __float_as_int(x), CTRL, 0xf, 0xf, true);
    return x + __int_as_float(r);
}

// ---- pre-pass: fp32->fp16 table cvt + q/feat row pre-gather ----
__global__ __launch_bounds__(256) void prep_kernel(
    const float* __restrict__ uv2e,   // [N, D] fp32
    const float* __restrict__ feat,   // [N, D] fp32
    const int*   __restrict__ nodes,  // [B]
    __half*      __restrict__ ktab,   // [N, D] fp16 (out)
    float*       __restrict__ qf,     // [B, 128] fp32 (out): q | feat
    int n8, int nblk_cvt, int B)
{
    const int bid = blockIdx.x;
    const int tid = threadIdx.x;
    if (bid < nblk_cvt) {
        int i = bid * 256 + tid;
        if (i >= n8) return;
        const float4* s4 = (const float4*)uv2e;
        float4 a = s4[2 * i];
        float4 b = s4[2 * i + 1];
        union { __half h[8]; uint4 u; } o;
        o.h[0] = __float2half(a.x); o.h[1] = __float2half(a.y);
        o.h[2] = __float2half(a.z); o.h[3] = __float2half(a.w);
        o.h[4] = __float2half(b.x); o.h[5] = __float2half(b.y);
        o.h[6] = __float2half(b.z); o.h[7] = __float2half(b.w);
        *(uint4*)(ktab + 8 * i) = o.u;
    } else {
        // qf chunks: u in [0, B*32), chunk = 4 floats
        int u = (bid - nblk_cvt) * 256 + tid;
        if (u >= B * 32) return;
        int row  = u >> 5;
        int c    = u & 31;
        int half = c >> 4;          // 0 = q, 1 = feat
        int t    = c & 15;
        int nid  = nodes[row];
        const float* src = (half ? feat : uv2e) + (size_t)nid * DD + 4 * t;
        float4 v = *(const float4*)src;
        *(float4*)(qf + (size_t)row * 128 + half * 64 + 4 * t) = v;
    }
}

__global__ __launch_bounds__(512, 6) void folded_encoder_kernel(
    const int*    __restrict__ node_seq,  // [B, S]
    const float*  __restrict__ W1,        // [D, 2D] row-major (out, in)
    const float*  __restrict__ b1,        // [D]
    const __half* __restrict__ ktab,      // [N, D] fp16
    const float*  __restrict__ qf,        // [B, 128]: q | feat
    float*        __restrict__ out,       // [B, D]
    int B)
{
    __shared__ __align__(16) float Wsw[DD][2 * DD];   // 32 KiB, swizzled chunks

    const int tid = threadIdx.x;
    const int wid = tid >> 6;
    const int ln  = tid & 63;
    const int g   = ln >> 4;        // S-quarter group
    const int t   = ln & 15;        // d-chunk: dims 4t..4t+3

    // ---- stage W1 -> LDS once per block (float4, XOR-swizzled chunks) ----
    #pragma unroll
    for (int r = 0; r < 4; ++r) {
        int chunk = r * 512 + tid;          // 0..2047 (16B chunks)
        int o = chunk >> 5;                 // output row 0..63
        int c = chunk & 31;                 // chunk within row
        float4 w = *(const float4*)(W1 + (size_t)chunk * 4);
        *(float4*)&Wsw[o][((c ^ (o & 7)) << 2)] = w;
    }
    const float bias = b1[ln];
    __syncthreads();

    // S-quarters: starts {0,12,25,37}, lens {12,13,12,13}
    const int start = (25 * g) >> 1;
    const int len   = ((25 * (g + 1)) >> 1) - start;

    #pragma unroll
    for (int b = 0; b < BATCHES; ++b) {
        const int row = (blockIdx.x * BATCHES + b) * WPB + wid;

        // q for this row (coalesced-ish from compact qf, L3-hot)
        const float4 q4 = *(const float4*)(qf + (size_t)row * 128 + 4 * t);

        // ---- neighbor ids: direct global loads (4 lines, L1/L2-hot) ----
        const int* sp = node_seq + (size_t)row * SS + start;
        int idxa[7], idxb[6];
        #pragma unroll
        for (int s = 0; s < 7; ++s) idxa[s] = sp[s < len ? s : 0];
        #pragma unroll
        for (int s = 0; s < 6; ++s) idxb[s] = sp[7 + s < len ? 7 + s : 0];

        // ---- gathers: two flights of 7 + 6 ----
        uint2 kra[7], krb[6];
        #pragma unroll
        for (int s = 0; s < 7; ++s)
            kra[s] = *(const uint2*)(ktab + (size_t)idxa[s] * DD + 4 * t);
        #pragma unroll
        for (int s = 0; s < 6; ++s)
            krb[s] = *(const uint2*)(ktab + (size_t)idxb[s] * DD + 4 * t);

        float  l   = 0.f;
        float4 acc = make_float4(0.f, 0.f, 0.f, 0.f);

        #pragma unroll
        for (int s = 0; s < 13; ++s) {
            union { uint2 u; __half h[4]; } kw;
            kw.u = (s < 7) ? kra[s] : krb[s - 7];
            float k0 = __half2float(kw.h[0]);
            float k1 = __half2float(kw.h[1]);
            float k2 = __half2float(kw.h[2]);
            float k3 = __half2float(kw.h[3]);

            float p = k0 * q4.x + k1 * q4.y + k2 * q4.z + k3 * q4.w;
            p = dpp_add<0xB1>(p);    // xor1 within quad
            p = dpp_add<0x4E>(p);    // xor2 within quad
            p = dpp_add<0x141>(p);   // row_half_mirror (8-group)
            p = dpp_add<0x140>(p);   // row_mirror (16-group)

            float e  = __builtin_amdgcn_exp2f(p * SCALE_L2E);
            float ee = (s < len) ? e : 0.f;   // tail predication
            l += ee;
            acc.x += ee * k0; acc.y += ee * k1;
            acc.z += ee * k2; acc.w += ee * k3;
        }

        // ---- merge the 4 S-quarters (lanes ^16, ^32) ----
        l     += __shfl_xor(l, 16);     l     += __shfl_xor(l, 32);
        acc.x += __shfl_xor(acc.x, 16); acc.x += __shfl_xor(acc.x, 32);
        acc.y += __shfl_xor(acc.y, 16); acc.y += __shfl_xor(acc.y, 32);
        acc.z += __shfl_xor(acc.z, 16); acc.z += __shfl_xor(acc.z, 32);
        acc.w += __shfl_xor(acc.w, 16); acc.w += __shfl_xor(acc.w, 32);

        const float rl = 1.0f / l;
        const float4 fold = make_float4(acc.x * rl, acc.y * rl, acc.z * rl, acc.w * rl);

        // feat row (needed only now — keeps mid-loop register pressure down)
        const float4 f4 = *(const float4*)(qf + (size_t)row * 128 + 64 + 4 * t);

        // ---- fused linear: out[row][o] = relu(b1[o] + comb . W1[o,:]) ----
        float oa0 = bias, oa1 = 0.f;
        const float* wrow = &Wsw[ln][0];
        #pragma unroll
        for (int cc = 0; cc < 32; ++cc) {
            float4 w4 = *(const float4*)&wrow[((cc ^ (ln & 7)) << 2)];
            const int srcl = cc & 15;
            float c0, c1, c2, c3;
            if (cc < 16) {
                c0 = rdlane_f(f4.x, srcl); c1 = rdlane_f(f4.y, srcl);
                c2 = rdlane_f(f4.z, srcl); c3 = rdlane_f(f4.w, srcl);
            } else {
                c0 = rdlane_f(fold.x, srcl); c1 = rdlane_f(fold.y, srcl);
                c2 = rdlane_f(fold.z, srcl); c3 = rdlane_f(fold.w, srcl);
            }
            oa0 += c0 * w4.x + c1 * w4.y;
            oa1 += c2 * w4.z + c3 * w4.w;
        }

        if (row < B)
            out[(size_t)row * DD + ln] = fmaxf(oa0 + oa1, 0.f);
    }
}

extern "C" void kernel_launch(void* const* d_in, const int* in_sizes, int n_in,
                              void* d_out, int out_size, void* d_ws, size_t ws_size,
                              hipStream_t stream) {
    const int*   nodes    = (const int*)  d_in[0];
    const int*   node_seq = (const int*)  d_in[1];
    const float* uv2e     = (const float*)d_in[2];
    const float* feat     = (const float*)d_in[3];
    const float* W1       = (const float*)d_in[4];
    const float* b1       = (const float*)d_in[5];
    float*       out      = (float*)d_out;

    const int B  = in_sizes[0];              // 8192
    const int NE = in_sizes[2];              // N*D = 6,400,000
    const int n8 = NE / 8;                   // 800,000 8-float chunks

    __half* ktab = (__half*)d_ws;                         // 12.8 MB
    float*  qf   = (float*)((char*)d_ws + (size_t)NE * 2); // 4 MB, 16B-aligned

    const int nblk_cvt = (n8 + 255) / 256;        // 3125
    const int nblk_qf  = (B * 32 + 255) / 256;    // 1024
    prep_kernel<<<nblk_cvt + nblk_qf, 256, 0, stream>>>(
        uv2e, feat, nodes, ktab, qf, n8, nblk_cvt, B);

    const int blocks = B / (BATCHES * WPB);       // 512
    folded_encoder_kernel<<<blocks, 512, 0, stream>>>(
        node_seq, W1, b1, ktab, qf, out, B);
}

// Round 13
// 110.796 us; speedup vs baseline: 1.1090x; 1.1090x over previous
//
#include <hip/hip_runtime.h>
#include <hip/hip_fp16.h>
#include <math.h>

// Folded_Encoder fused, round 11 (MI355X / gfx950).
// B=8192, S=50, D=64.
// prep:  pure streaming cvt uv2e fp32 -> fp16 ktab in d_ws (no gather phase).
// main:  1024 blocks x 512 thr (8 waves), 1 row/wave.
//        Wave = 4 S-quarter groups x 16 d-lanes (8B fp16 chunk per lane).
//        Neighbor ids: ONE coalesced load per wave (lanes 0..49) and 13
//        __shfl distributions per group -> all 13 k-gathers issue
//        back-to-back (no per-lane idx load latency in front of them).
//        q/feat gathered directly (overlaps k-gathers). exp2 softmax,
//        DPP 16-lane reduce, swizzled-LDS W1 epilogue + readlane broadcast.

#define DD      64
#define SS      50
#define WPB     8               // waves (= rows) per 512-thread block
#define SCALE_L2E 0.180336880f  // 0.125 * log2(e)

__device__ __forceinline__ float rdlane_f(float v, int l) {
    return __int_as_float(__builtin_amdgcn_readlane(__float_as_int(v), l));
}

template <int CTRL>
__device__ __forceinline__ float dpp_add(float x) {
    int r = __builtin_amdgcn_update_dpp(0, __float_as_int(x), CTRL, 0xf, 0xf, true);
    return x + __int_as_float(r);
}

// ---- pre-pass: fp32 table -> fp16 table (pure streaming, BW-bound) ----
__global__ __launch_bounds__(256) void cvt_f32_f16_kernel(
    const float* __restrict__ src, __half* __restrict__ dst, int n8)
{
    int i = blockIdx.x * blockDim.x + threadIdx.x;
    if (i >= n8) return;
    const float4* s4 = (const float4*)src;
    float4 a = s4[2 * i];
    float4 b = s4[2 * i + 1];
    union { __half h[8]; uint4 u; } o;
    o.h[0] = __float2half(a.x); o.h[1] = __float2half(a.y);
    o.h[2] = __float2half(a.z); o.h[3] = __float2half(a.w);
    o.h[4] = __float2half(b.x); o.h[5] = __float2half(b.y);
    o.h[6] = __float2half(b.z); o.h[7] = __float2half(b.w);
    *(uint4*)(dst + 8 * i) = o.u;
}

__global__ __launch_bounds__(512) void folded_encoder_kernel(
    const int*    __restrict__ nodes,     // [B]
    const int*    __restrict__ node_seq,  // [B, S]
    const float*  __restrict__ uv2e,      // [N, D] fp32 (q)
    const float*  __restrict__ feat,      // [N, D] fp32
    const float*  __restrict__ W1,        // [D, 2D] row-major (out, in)
    const float*  __restrict__ b1,        // [D]
    const __half* __restrict__ ktab,      // [N, D] fp16 (k = v)
    float*        __restrict__ out,       // [B, D]
    int B)
{
    __shared__ __align__(16) float Wsw[DD][2 * DD];   // 32 KiB, swizzled chunks

    const int tid = threadIdx.x;
    const int wid = tid >> 6;
    const int ln  = tid & 63;
    const int g   = ln >> 4;        // S-quarter group
    const int t   = ln & 15;        // d-chunk: dims 4t..4t+3

    const int row = blockIdx.x * WPB + wid;

    // ---- stage W1 -> LDS once per block (float4, XOR-swizzled chunks) ----
    #pragma unroll
    for (int r = 0; r < 4; ++r) {
        int chunk = r * 512 + tid;          // 0..2047 (16B chunks)
        int o = chunk >> 5;                 // output row 0..63
        int c = chunk & 31;                 // chunk within row
        float4 w = *(const float4*)(W1 + (size_t)chunk * 4);
        *(float4*)&Wsw[o][((c ^ (o & 7)) << 2)] = w;
    }

    // ---- ONE coalesced idx load per wave: lanes 0..49 hold the 50 ids ----
    const int sqv = node_seq[(size_t)row * SS + (ln < SS ? ln : SS - 1)];

    // q / feat rows gathered directly (random 256B; overlaps k-gathers)
    const int nid = nodes[row];
    const float4 q4 = *(const float4*)(uv2e + (size_t)nid * DD + 4 * t);

    const float bias = b1[ln];
    __syncthreads();

    // S-quarters: starts {0,12,25,37}, lens {12,13,12,13}
    const int start = (25 * g) >> 1;
    const int len   = ((25 * (g + 1)) >> 1) - start;

    // ---- 13 k-gathers issued back-to-back, addresses via shfl (LDS pipe) ----
    uint2 kr[13];
    #pragma unroll
    for (int s = 0; s < 13; ++s) {
        int idx = __shfl(sqv, start + (s < len ? s : 0));
        kr[s] = *(const uint2*)(ktab + (size_t)idx * DD + 4 * t);
    }

    // ---- subtraction-free exp2-domain softmax over this quarter ----
    float  l   = 0.f;
    float4 acc = make_float4(0.f, 0.f, 0.f, 0.f);
    #pragma unroll
    for (int s = 0; s < 13; ++s) {
        union { uint2 u; __half h[4]; } kw; kw.u = kr[s];
        float k0 = __half2float(kw.h[0]);
        float k1 = __half2float(kw.h[1]);
        float k2 = __half2float(kw.h[2]);
        float k3 = __half2float(kw.h[3]);

        float p = k0 * q4.x + k1 * q4.y + k2 * q4.z + k3 * q4.w;
        p = dpp_add<0xB1>(p);    // xor1 within quad
        p = dpp_add<0x4E>(p);    // xor2 within quad
        p = dpp_add<0x141>(p);   // row_half_mirror (8-group)
        p = dpp_add<0x140>(p);   // row_mirror (16-group)

        float e  = __builtin_amdgcn_exp2f(p * SCALE_L2E);
        float ee = (s < len) ? e : 0.f;   // tail predication
        l += ee;
        acc.x += ee * k0; acc.y += ee * k1;
        acc.z += ee * k2; acc.w += ee * k3;
    }

    // ---- merge the 4 S-quarters (lanes ^16, ^32) ----
    l     += __shfl_xor(l, 16);     l     += __shfl_xor(l, 32);
    acc.x += __shfl_xor(acc.x, 16); acc.x += __shfl_xor(acc.x, 32);
    acc.y += __shfl_xor(acc.y, 16); acc.y += __shfl_xor(acc.y, 32);
    acc.z += __shfl_xor(acc.z, 16); acc.z += __shfl_xor(acc.z, 32);
    acc.w += __shfl_xor(acc.w, 16); acc.w += __shfl_xor(acc.w, 32);

    const float rl = 1.0f / l;
    const float4 fold = make_float4(acc.x * rl, acc.y * rl, acc.z * rl, acc.w * rl);

    // feat row loaded late (keeps mid-loop register pressure down)
    const float4 f4 = *(const float4*)(feat + (size_t)nid * DD + 4 * t);

    // ---- fused linear: out[row][o] = relu(b1[o] + comb . W1[o,:]) ----
    float oa0 = bias, oa1 = 0.f;
    const float* wrow = &Wsw[ln][0];
    #pragma unroll
    for (int cc = 0; cc < 32; ++cc) {
        float4 w4 = *(const float4*)&wrow[((cc ^ (ln & 7)) << 2)];
        const int srcl = cc & 15;
        float c0, c1, c2, c3;
        if (cc < 16) {
            c0 = rdlane_f(f4.x, srcl); c1 = rdlane_f(f4.y, srcl);
            c2 = rdlane_f(f4.z, srcl); c3 = rdlane_f(f4.w, srcl);
        } else {
            c0 = rdlane_f(fold.x, srcl); c1 = rdlane_f(fold.y, srcl);
            c2 = rdlane_f(fold.z, srcl); c3 = rdlane_f(fold.w, srcl);
        }
        oa0 += c0 * w4.x + c1 * w4.y;
        oa1 += c2 * w4.z + c3 * w4.w;
    }

    if (row < B)
        out[(size_t)row * DD + ln] = fmaxf(oa0 + oa1, 0.f);
}

extern "C" void kernel_launch(void* const* d_in, const int* in_sizes, int n_in,
                              void* d_out, int out_size, void* d_ws, size_t ws_size,
                              hipStream_t stream) {
    const int*   nodes    = (const int*)  d_in[0];
    const int*   node_seq = (const int*)  d_in[1];
    const float* uv2e     = (const float*)d_in[2];
    const float* feat     = (const float*)d_in[3];
    const float* W1       = (const float*)d_in[4];
    const float* b1       = (const float*)d_in[5];
    float*       out      = (float*)d_out;

    const int B  = in_sizes[0];              // 8192
    const int NE = in_sizes[2];              // N*D = 6,400,000
    const int n8 = NE / 8;                   // 800,000 8-float chunks

    __half* ktab = (__half*)d_ws;            // 12.8 MB << ws_size

    cvt_f32_f16_kernel<<<(n8 + 255) / 256, 256, 0, stream>>>(uv2e, ktab, n8);

    const int blocks = (B + WPB - 1) / WPB;  // 1024 blocks x 512 threads
    folded_encoder_kernel<<<blocks, 512, 0, stream>>>(
        nodes, node_seq, uv2e, feat, W1, b1, ktab, out, B);
}